// Round 3
// baseline (561.743 us; speedup 1.0000x reference)
//
#include <hip/hip_runtime.h>
#include <math.h>

#define NTOK 16384
#define KCB  4096
#define DIM  128
#define KSPLIT 16
#define CPW (KCB / KSPLIT)   // codes per wave-block in k_argmin

// ---------------------------------------------------------------------------
// ws layout (float offsets):
//   [0..2]  accum: 0=mse_sum, 1=cos_sum, 2=pair_sum
//   [3]     minbits (unsigned, +inf init)
//   [8]     best[NTOK]  (unsigned long long, packed (dist_bits<<32)|idx)
//   [8+2*NTOK]          sumx2[NTOK]
//   [..]                sumc2[KCB]
//   [..]                cnt[KCB] (int)
// ---------------------------------------------------------------------------

__global__ __launch_bounds__(256) void k_init(float* __restrict__ accum,
                                              unsigned* __restrict__ minbits,
                                              unsigned long long* __restrict__ best,
                                              int* __restrict__ cnt) {
  const int t = threadIdx.x;
  if (t < 3) accum[t] = 0.0f;
  if (t == 3) *minbits = 0x7F800000u;  // +inf
  for (int k = t; k < KCB; k += 256) cnt[k] = 0;
  for (int i = t; i < NTOK; i += 256) best[i] = 0xFFFFFFFFFFFFFFFFull;
}

// Row sum-of-squares in fp64, rounded once to fp32.
__global__ __launch_bounds__(256) void k_rownorm(const float* __restrict__ lat,
                                                 const float* __restrict__ cb,
                                                 float* __restrict__ sumx2,
                                                 float* __restrict__ sumc2) {
  const int row  = blockIdx.x * 4 + (threadIdx.x >> 6);
  const int lane = threadIdx.x & 63;
  const float* src = (row < NTOK) ? (lat + (size_t)row * DIM)
                                  : (cb + (size_t)(row - NTOK) * DIM);
  float2 v = *(const float2*)(src + lane * 2);
  double s = (double)v.x * (double)v.x + (double)v.y * (double)v.y;
#pragma unroll
  for (int m = 32; m >= 1; m >>= 1) s += __shfl_xor(s, m, 64);
  if (lane == 0) {
    if (row < NTOK) sumx2[row] = (float)s;
    else            sumc2[row - NTOK] = (float)s;
  }
}

// lane = token (A resident in 128 VGPRs); codes stream via wave-uniform loads
// (SGPR / scalar pipe). dist chain identical to rounds 1-2 (d ascending fmaf,
// dist = (sx - 2*acc) + q). Packed atomicMin implements strict-<, lowest-idx
// tie-break exactly (dist > 0 always: ||x||^2 ~ 128 dominates).
__global__ __launch_bounds__(64, 3) void k_argmin(const float* __restrict__ lat,
                                                  const float* __restrict__ cb,
                                                  const float* __restrict__ sumx2,
                                                  const float* __restrict__ sumc2,
                                                  unsigned long long* __restrict__ best) {
  const int lane = threadIdx.x;
  const int tok  = blockIdx.x * 64 + lane;
  const int kbase = blockIdx.y * CPW;

  float a[DIM];
  {
    const float4* ap = (const float4*)(lat + (size_t)tok * DIM);
#pragma unroll
    for (int i = 0; i < DIM / 4; ++i) {
      const float4 v = ap[i];
      a[4 * i + 0] = v.x; a[4 * i + 1] = v.y;
      a[4 * i + 2] = v.z; a[4 * i + 3] = v.w;
    }
  }
  const float sx = sumx2[tok];

  float bd = INFINITY;
  int   bi = 0;

  const float4* __restrict__ cb4 = (const float4*)cb;

#pragma unroll 1
  for (int g = 0; g < CPW; g += 4) {
    const int c0 = kbase + g;
    float acc0 = 0.0f, acc1 = 0.0f, acc2 = 0.0f, acc3 = 0.0f;
#pragma unroll
    for (int ch = 0; ch < DIM / 4; ++ch) {
      const float4 b0 = cb4[(size_t)(c0 + 0) * (DIM / 4) + ch];
      const float4 b1 = cb4[(size_t)(c0 + 1) * (DIM / 4) + ch];
      const float4 b2 = cb4[(size_t)(c0 + 2) * (DIM / 4) + ch];
      const float4 b3 = cb4[(size_t)(c0 + 3) * (DIM / 4) + ch];
      const float a0 = a[4 * ch + 0], a1 = a[4 * ch + 1];
      const float a2 = a[4 * ch + 2], a3 = a[4 * ch + 3];
      acc0 = fmaf(a0, b0.x, acc0); acc1 = fmaf(a0, b1.x, acc1);
      acc2 = fmaf(a0, b2.x, acc2); acc3 = fmaf(a0, b3.x, acc3);
      acc0 = fmaf(a1, b0.y, acc0); acc1 = fmaf(a1, b1.y, acc1);
      acc2 = fmaf(a1, b2.y, acc2); acc3 = fmaf(a1, b3.y, acc3);
      acc0 = fmaf(a2, b0.z, acc0); acc1 = fmaf(a2, b1.z, acc1);
      acc2 = fmaf(a2, b2.z, acc2); acc3 = fmaf(a2, b3.z, acc3);
      acc0 = fmaf(a3, b0.w, acc0); acc1 = fmaf(a3, b1.w, acc1);
      acc2 = fmaf(a3, b2.w, acc2); acc3 = fmaf(a3, b3.w, acc3);
    }
    const float q0 = sumc2[c0 + 0], q1 = sumc2[c0 + 1];
    const float q2 = sumc2[c0 + 2], q3 = sumc2[c0 + 3];
    const float d0 = (sx - 2.0f * acc0) + q0;
    const float d1 = (sx - 2.0f * acc1) + q1;
    const float d2 = (sx - 2.0f * acc2) + q2;
    const float d3 = (sx - 2.0f * acc3) + q3;
    if (d0 < bd) { bd = d0; bi = c0 + 0; }
    if (d1 < bd) { bd = d1; bi = c0 + 1; }
    if (d2 < bd) { bd = d2; bi = c0 + 2; }
    if (d3 < bd) { bd = d3; bi = c0 + 3; }
  }

  const unsigned long long pack =
      ((unsigned long long)__float_as_uint(bd) << 32) | (unsigned)bi;
  atomicMin(&best[tok], pack);
}

// Gather quantized_st, mse + sel_cos partials, histogram.
__global__ __launch_bounds__(256) void k_gather(const float* __restrict__ lat,
                                                const float* __restrict__ cb,
                                                const float* __restrict__ sumx2,
                                                const float* __restrict__ sumc2,
                                                const unsigned long long* __restrict__ best,
                                                float* __restrict__ qout,
                                                float* __restrict__ idx_out,
                                                float* __restrict__ accum,
                                                int* __restrict__ cnt) {
  const int wave = threadIdx.x >> 6, lane = threadIdx.x & 63;
  __shared__ float sm[8];
  float msel = 0.0f, cosl = 0.0f;
  const int base = blockIdx.x * 64 + wave * 16;
  for (int it = 0; it < 16; ++it) {
    const int tok = base + it;
    const int code = (int)(best[tok] & 0xFFFFFFFFull);
    float2 l2 = *(const float2*)(lat + (size_t)tok * DIM + lane * 2);
    float2 c2 = *(const float2*)(cb + (size_t)code * DIM + lane * 2);
    const float o0 = l2.x + (c2.x - l2.x);
    const float o1 = l2.y + (c2.y - l2.y);
    *(float2*)(qout + (size_t)tok * DIM + lane * 2) = make_float2(o0, o1);
    const float e0 = l2.x - c2.x, e1 = l2.y - c2.y;
    msel += e0 * e0 + e1 * e1;
    float dt = l2.x * c2.x + l2.y * c2.y;
#pragma unroll
    for (int m = 32; m >= 1; m >>= 1) dt += __shfl_xor(dt, m, 64);
    if (lane == 0) {
      const float nx = fmaxf(sqrtf(sumx2[tok]), 1e-12f);
      const float nc = fmaxf(sqrtf(sumc2[code]), 1e-12f);
      cosl += dt / (nx * nc);
      idx_out[tok] = (float)code;
      atomicAdd(&cnt[code], 1);
    }
  }
#pragma unroll
  for (int m = 32; m >= 1; m >>= 1) msel += __shfl_xor(msel, m, 64);
  if (lane == 0) { sm[wave] = msel; sm[4 + wave] = cosl; }
  __syncthreads();
  if (threadIdx.x == 0) {
    atomicAdd(&accum[0], sm[0] + sm[1] + sm[2] + sm[3]);
    atomicAdd(&accum[1], sm[4] + sm[5] + sm[6] + sm[7]);
  }
}

// Codebook pairwise: lane = code_j (in VGPRs), stream code_k via uniform loads.
// Upper-triangular 64x64 chunk grid; off-diagonal chunks scaled x2.
__global__ __launch_bounds__(64, 3) void k_pair(const float* __restrict__ cb,
                                                const float* __restrict__ sumc2,
                                                float* __restrict__ accum,
                                                unsigned* __restrict__ minbits) {
  const int bj = blockIdx.y, bk = blockIdx.x;
  if (bk < bj) return;
  const int lane = threadIdx.x;
  const int j = bj * 64 + lane;

  float a[DIM];
  {
    const float4* ap = (const float4*)(cb + (size_t)j * DIM);
#pragma unroll
    for (int i = 0; i < DIM / 4; ++i) {
      const float4 v = ap[i];
      a[4 * i + 0] = v.x; a[4 * i + 1] = v.y;
      a[4 * i + 2] = v.z; a[4 * i + 3] = v.w;
    }
  }
  const float qj = sumc2[j];

  float lsum = 0.0f, lmin = INFINITY;
  const float4* __restrict__ cb4 = (const float4*)cb;

#pragma unroll 1
  for (int kk = 0; kk < 64; kk += 4) {
    const int c0 = bk * 64 + kk;
    float acc0 = 0.0f, acc1 = 0.0f, acc2 = 0.0f, acc3 = 0.0f;
#pragma unroll
    for (int ch = 0; ch < DIM / 4; ++ch) {
      const float4 b0 = cb4[(size_t)(c0 + 0) * (DIM / 4) + ch];
      const float4 b1 = cb4[(size_t)(c0 + 1) * (DIM / 4) + ch];
      const float4 b2 = cb4[(size_t)(c0 + 2) * (DIM / 4) + ch];
      const float4 b3 = cb4[(size_t)(c0 + 3) * (DIM / 4) + ch];
      const float a0 = a[4 * ch + 0], a1 = a[4 * ch + 1];
      const float a2 = a[4 * ch + 2], a3 = a[4 * ch + 3];
      acc0 = fmaf(a0, b0.x, acc0); acc1 = fmaf(a0, b1.x, acc1);
      acc2 = fmaf(a0, b2.x, acc2); acc3 = fmaf(a0, b3.x, acc3);
      acc0 = fmaf(a1, b0.y, acc0); acc1 = fmaf(a1, b1.y, acc1);
      acc2 = fmaf(a1, b2.y, acc2); acc3 = fmaf(a1, b3.y, acc3);
      acc0 = fmaf(a2, b0.z, acc0); acc1 = fmaf(a2, b1.z, acc1);
      acc2 = fmaf(a2, b2.z, acc2); acc3 = fmaf(a2, b3.z, acc3);
      acc0 = fmaf(a3, b0.w, acc0); acc1 = fmaf(a3, b1.w, acc1);
      acc2 = fmaf(a3, b2.w, acc2); acc3 = fmaf(a3, b3.w, acc3);
    }
    const float q0 = sumc2[c0 + 0], q1 = sumc2[c0 + 1];
    const float q2 = sumc2[c0 + 2], q3 = sumc2[c0 + 3];
    const float dd0 = sqrtf(fmaxf((qj + q0) - 2.0f * acc0, 0.0f));
    const float dd1 = sqrtf(fmaxf((qj + q1) - 2.0f * acc1, 0.0f));
    const float dd2 = sqrtf(fmaxf((qj + q2) - 2.0f * acc2, 0.0f));
    const float dd3 = sqrtf(fmaxf((qj + q3) - 2.0f * acc3, 0.0f));
    lsum += dd0 + dd1 + dd2 + dd3;
    if (j != c0 + 0) lmin = fminf(lmin, dd0);
    if (j != c0 + 1) lmin = fminf(lmin, dd1);
    if (j != c0 + 2) lmin = fminf(lmin, dd2);
    if (j != c0 + 3) lmin = fminf(lmin, dd3);
  }

  const float scale = (bj == bk) ? 1.0f : 2.0f;
#pragma unroll
  for (int m = 32; m >= 1; m >>= 1) {
    lsum += __shfl_xor(lsum, m, 64);
    lmin = fminf(lmin, __shfl_xor(lmin, m, 64));
  }
  if (lane == 0) {
    atomicAdd(&accum[2], lsum * scale);
    atomicMin(minbits, __float_as_uint(lmin));
  }
}

__global__ __launch_bounds__(256) void k_final(const int* __restrict__ cnt,
                                               const float* __restrict__ accum,
                                               const unsigned* __restrict__ minbits,
                                               float* __restrict__ outs) {
  __shared__ float sh[256];
  const int t = threadIdx.x;
  float ent = 0.0f;
  for (int k = t; k < KCB; k += 256) {
    const float p = (float)cnt[k] * (1.0f / (float)NTOK);
    ent += p * logf(p + 1e-10f);
  }
  sh[t] = ent;
  __syncthreads();
  for (int s = 128; s >= 1; s >>= 1) {
    if (t < s) sh[t] += sh[t + s];
    __syncthreads();
  }
  if (t == 0) {
    const float mse = accum[0] * (1.0f / (float)(NTOK * DIM));
    outs[0] = 0.25f * mse;
    outs[1] = mse;
    outs[2] = expf(-sh[0]);
    outs[3] = accum[1] * (1.0f / (float)NTOK);
    outs[4] = accum[2] / ((float)KCB * (float)(KCB - 1));
    outs[5] = __uint_as_float(*minbits);
  }
}

extern "C" void kernel_launch(void* const* d_in, const int* in_sizes, int n_in,
                              void* d_out, int out_size, void* d_ws, size_t ws_size,
                              hipStream_t stream) {
  const float* lat = (const float*)d_in[0];
  const float* cb  = (const float*)d_in[1];

  float* out     = (float*)d_out;
  float* qout    = out;
  float* idx_out = out + (size_t)NTOK * DIM;
  float* outs    = idx_out + NTOK;

  float* W       = (float*)d_ws;
  float* accum   = W;                                  // 3 floats
  unsigned* minb = (unsigned*)(W + 3);
  unsigned long long* best = (unsigned long long*)(W + 8);  // NTOK u64
  float* sumx2   = W + 8 + 2 * NTOK;                   // NTOK
  float* sumc2   = sumx2 + NTOK;                       // KCB
  int*   cnt     = (int*)(sumc2 + KCB);                // KCB

  hipLaunchKernelGGL(k_init, dim3(1), dim3(256), 0, stream, accum, minb, best, cnt);
  hipLaunchKernelGGL(k_rownorm, dim3((NTOK + KCB) / 4), dim3(256), 0, stream,
                     lat, cb, sumx2, sumc2);
  hipLaunchKernelGGL(k_argmin, dim3(NTOK / 64, KSPLIT), dim3(64), 0, stream,
                     lat, cb, sumx2, sumc2, best);
  hipLaunchKernelGGL(k_pair, dim3(KCB / 64, KCB / 64), dim3(64), 0, stream,
                     cb, sumc2, accum, minb);
  hipLaunchKernelGGL(k_gather, dim3(NTOK / 64), dim3(256), 0, stream,
                     lat, cb, sumx2, sumc2, best, qout, idx_out, accum, cnt);
  hipLaunchKernelGGL(k_final, dim3(1), dim3(256), 0, stream, cnt, accum, minb, outs);
}